// Round 1
// baseline (509.104 us; speedup 1.0000x reference)
//
#include <hip/hip_runtime.h>
#include <math.h>

#define NRES 512
#define HH 12
#define PQn 4
#define PVn 8
#define En 16
#define Cn 128
#define Sn 384
#define ATT_COLS 2112   // 192 att_single | 1536 att_pair | 288 points | 96 norms

// workspace float offsets
#define OFF_Q    0
#define OFF_K    (OFF_Q   + HH*NRES*En)     // 98304
#define OFF_V    (OFF_K   + HH*NRES*En)
#define OFF_LQP  (OFF_V   + HH*NRES*En)     // 294912
#define OFF_LKP  (OFF_LQP + HH*NRES*12)
#define OFF_LVP  (OFF_LKP + HH*NRES*12)
#define OFF_CS   (OFF_LVP + HH*NRES*24)     // colsumT [NRES][HH]
#define OFF_ATT  (OFF_CS  + NRES*HH)        // att [NRES][ATT_COLS]

// ---------------------------------------------------------------------------
// Kernel A: projections q/k/v (E=16 each) and point projections qp/kp/vp with
// frame application (lqp/lkp/lvp). 8 residues per block so weights are reused.
// grid (64, 8): y = column-group g (0..5 = qkv units, 6..7 = point units)
// ---------------------------------------------------------------------------
__global__ __launch_bounds__(256) void ipa_proj(
    const float* __restrict__ single, const float* __restrict__ Rm,
    const float* __restrict__ tr,
    const float* __restrict__ Wq, const float* __restrict__ Wk,
    const float* __restrict__ Wv, const float* __restrict__ Wqp,
    const float* __restrict__ Wkp, const float* __restrict__ Wvp,
    float* __restrict__ ws)
{
  float* q   = ws + OFF_Q;  float* k   = ws + OFF_K;  float* v   = ws + OFF_V;
  float* lqp = ws + OFF_LQP; float* lkp = ws + OFF_LKP; float* lvp = ws + OFF_LVP;
  const int n0 = blockIdx.x * 8;
  const int g  = blockIdx.y;
  const int tid = threadIdx.x;
  __shared__ float sS[8][388];   // pad 388: bank spread for 8-row access
  __shared__ float sR[8][9];
  __shared__ float sT[8][3];
  #pragma unroll
  for (int i = 0; i < 3; ++i) {
    int idx = i*256 + tid;           // 0..767 float4 units (8 rows x 96)
    int r = idx / 96, c4 = idx % 96;
    float4 val = *reinterpret_cast<const float4*>(single + (size_t)(n0 + r)*Sn + c4*4);
    *reinterpret_cast<float4*>(&sS[r][c4*4]) = val;
  }
  if (tid < 72)      sR[tid/9][tid%9] = Rm[(size_t)(n0 + tid/9)*9 + tid%9];
  else if (tid < 96) { int r = (tid-72)/3; sT[r][(tid-72)%3] = tr[(size_t)(n0+r)*3 + (tid-72)%3]; }
  __syncthreads();
  #pragma unroll
  for (int i = 0; i < 3; ++i) {
    int item = i*256 + tid;          // 0..767
    int nl = item & 7;
    int ul = item >> 3;              // 0..95
    int u  = g*96 + ul;              // global unit 0..767
    const float* srow = sS[nl];
    if (u < 576) {                   // q/k/v scalar column
      int which = u/192, r = u%192, h = r>>4, e = r&15;
      const float* W = (which==0 ? Wq : which==1 ? Wk : Wv) + (size_t)h*Sn*En + e;
      float acc = 0.f;
      #pragma unroll 8
      for (int d = 0; d < Sn; ++d) acc = fmaf(srow[d], W[(size_t)d*En], acc);
      float* dst = (which==0 ? q : which==1 ? k : v);
      dst[((size_t)h*NRES + (n0+nl))*En + e] = acc;
    } else {                         // point unit: 3 dots + frame apply
      int u2 = u - 576;
      const float* W; float* dst;
      if (u2 < 48)      { int h=u2>>2,     p=u2&3;      W = Wqp + (size_t)(h*PQn+p)*Sn*3; dst = lqp + ((size_t)h*NRES + (n0+nl))*12 + p*3; }
      else if (u2 < 96) { int h=(u2-48)>>2,p=(u2-48)&3; W = Wkp + (size_t)(h*PQn+p)*Sn*3; dst = lkp + ((size_t)h*NRES + (n0+nl))*12 + p*3; }
      else              { int h=(u2-96)>>3,p=(u2-96)&7; W = Wvp + (size_t)(h*PVn+p)*Sn*3; dst = lvp + ((size_t)h*NRES + (n0+nl))*24 + p*3; }
      float x0=0.f,x1=0.f,x2=0.f;
      #pragma unroll 4
      for (int d = 0; d < Sn; ++d) {
        float sv = srow[d];
        x0 = fmaf(sv, W[d*3+0], x0);
        x1 = fmaf(sv, W[d*3+1], x1);
        x2 = fmaf(sv, W[d*3+2], x2);
      }
      const float* R8 = sR[nl]; const float* T8 = sT[nl];
      dst[0] = R8[0]*x0 + R8[1]*x1 + R8[2]*x2 + T8[0];
      dst[1] = R8[3]*x0 + R8[4]*x1 + R8[5]*x2 + T8[1];
      dst[2] = R8[6]*x0 + R8[7]*x1 + R8[8]*x2 + T8[2];
    }
  }
}

// ---------------------------------------------------------------------------
// Kernel B: one block per query residue n (512 blocks, 256 threads).
// Phase 1: pair-bias logits (LDS-staged pair tiles, Wb via uniform loads)
// Phase 2: + qk term + frame-distance term
// Phase 3: per-wave softmax (wave w owns heads 3w..3w+2) + colsum atomics
// Phase 4: att_single = w.v  and local_out = w.lvp
// Phase 5: inverse frame, points + norms into att
// ---------------------------------------------------------------------------
__global__ __launch_bounds__(256) void ipa_attn(
    const float* __restrict__ pair, const float* __restrict__ Wb,
    const float* __restrict__ scale_head,
    const float* __restrict__ Rm, const float* __restrict__ tr,
    float* __restrict__ ws)
{
  const float* q   = ws + OFF_Q;  const float* k   = ws + OFF_K;
  const float* v   = ws + OFF_V;  const float* lqp = ws + OFF_LQP;
  const float* lkp = ws + OFF_LKP; const float* lvp = ws + OFF_LVP;
  float* colsumT = ws + OFF_CS;
  float* att     = ws + OFF_ATT;
  const int n    = blockIdx.x;
  const int tid  = threadIdx.x;
  const int lane = tid & 63;
  const int wave = tid >> 6;       // 0..3
  const int h0   = wave*3;

  __shared__ float tile[64*132];   // 64 m-rows x 128 c, pad->132 (8-window b128)
  __shared__ float logits[HH][NRES];
  __shared__ float4 sPart[120];
  __shared__ float sLoc[HH][24];

  const float* prow = pair + (size_t)n*NRES*Cn;

  // ---- phase 1: pair bias ----
  for (int mt = 0; mt < 8; ++mt) {
    __syncthreads();
    #pragma unroll
    for (int i = 0; i < 8; ++i) {
      int idx = i*256 + tid;       // 0..2047 float4 units (64 rows x 32)
      int r = idx >> 5, cf = idx & 31;
      float4 val = *reinterpret_cast<const float4*>(prow + (size_t)(mt*64 + r)*Cn + cf*4);
      *reinterpret_cast<float4*>(&tile[r*132 + cf*4]) = val;
    }
    __syncthreads();
    float p0=0.f, p1=0.f, p2=0.f;
    #pragma unroll 8
    for (int c4 = 0; c4 < 32; ++c4) {
      float4 pv = *reinterpret_cast<const float4*>(&tile[lane*132 + c4*4]);
      float4 w0 = *reinterpret_cast<const float4*>(Wb + (h0+0)*Cn + c4*4); // uniform -> s_load
      float4 w1 = *reinterpret_cast<const float4*>(Wb + (h0+1)*Cn + c4*4);
      float4 w2 = *reinterpret_cast<const float4*>(Wb + (h0+2)*Cn + c4*4);
      p0 += pv.x*w0.x + pv.y*w0.y + pv.z*w0.z + pv.w*w0.w;
      p1 += pv.x*w1.x + pv.y*w1.y + pv.z*w1.z + pv.w*w1.w;
      p2 += pv.x*w2.x + pv.y*w2.y + pv.z*w2.z + pv.w*w2.w;
    }
    logits[h0+0][mt*64+lane] = p0;
    logits[h0+1][mt*64+lane] = p1;
    logits[h0+2][mt*64+lane] = p2;
  }
  __syncthreads();

  // ---- phase 2: qk + frame terms ----
  #pragma unroll
  for (int rep = 0; rep < 2; ++rep) {
    const int m = rep*256 + tid;
    #pragma unroll
    for (int h = 0; h < HH; ++h) {
      const float* qh = q + ((size_t)h*NRES + n)*En;   // uniform
      const float* kh = k + ((size_t)h*NRES + m)*En;
      float qk = 0.f;
      #pragma unroll
      for (int e = 0; e < En; ++e) qk = fmaf(qh[e], kh[e], qk);
      const float* lq = lqp + ((size_t)h*NRES + n)*12; // uniform
      const float* lk = lkp + ((size_t)h*NRES + m)*12;
      float cross=0.f, Bm=0.f, An=0.f;
      #pragma unroll
      for (int jj = 0; jj < 12; ++jj) {
        float a = lq[jj], b = lk[jj];
        cross = fmaf(a, b, cross); Bm = fmaf(b, b, Bm); An = fmaf(a, a, An);
      }
      // gamma = sqrt(1/(18*PQ)) * softplus(scale_head)
      float gamma = 0.11785113019775793f * log1pf(__expf(scale_head[h]));
      logits[h][m] += 0.25f*qk - gamma*(An + Bm - 2.f*cross);
    }
  }
  __syncthreads();

  // ---- phase 3: softmax per head (wave-local) + colsum ----
  #pragma unroll
  for (int hh = 0; hh < 3; ++hh) {
    const int h = h0 + hh;
    float x[8];
    float mx = -3.4e38f;
    #pragma unroll
    for (int jj = 0; jj < 8; ++jj) { x[jj] = logits[h][lane + 64*jj]; mx = fmaxf(mx, x[jj]); }
    #pragma unroll
    for (int off = 32; off >= 1; off >>= 1) mx = fmaxf(mx, __shfl_xor(mx, off));
    float sum = 0.f;
    #pragma unroll
    for (int jj = 0; jj < 8; ++jj) { x[jj] = __expf(x[jj]-mx); sum += x[jj]; }
    #pragma unroll
    for (int off = 32; off >= 1; off >>= 1) sum += __shfl_xor(sum, off);
    const float inv = 1.f/sum;
    #pragma unroll
    for (int jj = 0; jj < 8; ++jj) {
      float wv = x[jj]*inv;
      logits[h][lane+64*jj] = wv;
      atomicAdd(&colsumT[(size_t)(lane+64*jj)*HH + h], wv);
    }
  }
  __syncthreads();

  // ---- phase 4: w.v and w.lvp ----
  float4 acc = make_float4(0.f,0.f,0.f,0.f);
  int mh=0, r=0, h4=0, j4=0;
  if (tid < 240) {
    mh = tid/120; r = tid%120; h4 = r/10; j4 = r%10;
    const float* src; int stride;
    if (j4 < 4) { src = v   + ((size_t)h4*NRES)*En + j4*4;     stride = En; }
    else        { src = lvp + ((size_t)h4*NRES)*24 + (j4-4)*4; stride = 24; }
    src += (size_t)(mh*256)*stride;
    for (int mm = 0; mm < 256; ++mm) {
      float wv = logits[h4][mh*256 + mm];
      float4 xv = *reinterpret_cast<const float4*>(src + (size_t)mm*stride);
      acc.x = fmaf(wv, xv.x, acc.x);
      acc.y = fmaf(wv, xv.y, acc.y);
      acc.z = fmaf(wv, xv.z, acc.z);
      acc.w = fmaf(wv, xv.w, acc.w);
    }
  }
  if (tid < 120) sPart[r] = acc;            // mh==0 half
  __syncthreads();
  if (tid >= 120 && tid < 240) {            // mh==1 half combines
    float4 o = sPart[r];
    o.x += acc.x; o.y += acc.y; o.z += acc.z; o.w += acc.w;
    if (j4 < 4) {
      *reinterpret_cast<float4*>(att + (size_t)n*ATT_COLS + h4*En + j4*4) = o;
    } else {
      sLoc[h4][(j4-4)*4+0] = o.x; sLoc[h4][(j4-4)*4+1] = o.y;
      sLoc[h4][(j4-4)*4+2] = o.z; sLoc[h4][(j4-4)*4+3] = o.w;
    }
  }
  __syncthreads();

  // ---- phase 5: inverse frame -> points + norms ----
  if (tid < 96) {
    const int h = tid/8, p = tid%8;
    float l0 = sLoc[h][p*3+0], l1 = sLoc[h][p*3+1], l2 = sLoc[h][p*3+2];
    float R0=Rm[n*9+0],R1=Rm[n*9+1],R2=Rm[n*9+2],
          R3=Rm[n*9+3],R4=Rm[n*9+4],R5=Rm[n*9+5],
          R6=Rm[n*9+6],R7=Rm[n*9+7],R8=Rm[n*9+8];
    float d0 = l0 - tr[n*3+0], d1 = l1 - tr[n*3+1], d2 = l2 - tr[n*3+2];
    float g0 = R0*d0 + R3*d1 + R6*d2;   // R^T (l - t)
    float g1 = R1*d0 + R4*d1 + R7*d2;
    float g2 = R2*d0 + R5*d1 + R8*d2;
    size_t base = (size_t)n*ATT_COLS;
    att[base + 1728 + (p*HH + h)*3 + 0] = g0;
    att[base + 1728 + (p*HH + h)*3 + 1] = g1;
    att[base + 1728 + (p*HH + h)*3 + 2] = g2;
    att[base + 2016 + p*HH + h] = sqrtf(g0*g0 + g1*g1 + g2*g2);
  }
}

// ---------------------------------------------------------------------------
// Kernel C: att_pair[h,i,c] = sum_b colsum[h,b]*pair[i,b,c]. One block per i.
// ---------------------------------------------------------------------------
__global__ __launch_bounds__(256) void ipa_pairagg(
    const float* __restrict__ pair, float* __restrict__ ws)
{
  const float* colsumT = ws + OFF_CS;
  float* att = ws + OFF_ATT;
  const int i = blockIdx.x, tid = threadIdx.x;
  __shared__ float sCS[NRES*HH];       // [b][h], 24KB
  __shared__ float4 sRed[8][HH][32];   // 48KB
  #pragma unroll
  for (int it = 0; it < 6; ++it) {
    int idx = it*256 + tid;
    reinterpret_cast<float4*>(sCS)[idx] = reinterpret_cast<const float4*>(colsumT)[idx];
  }
  __syncthreads();
  const int c4 = tid & 31, bg = tid >> 5;
  float4 acc[HH];
  #pragma unroll
  for (int h = 0; h < HH; ++h) acc[h] = make_float4(0.f,0.f,0.f,0.f);
  const float* prow = pair + (size_t)i*NRES*Cn;
  for (int b = bg; b < NRES; b += 8) {
    float4 pv = *reinterpret_cast<const float4*>(prow + (size_t)b*Cn + c4*4);
    const float4* cs = reinterpret_cast<const float4*>(&sCS[b*HH]); // uniform per half-wave
    float4 c0 = cs[0], c1 = cs[1], c2 = cs[2];
    float w[12] = {c0.x,c0.y,c0.z,c0.w, c1.x,c1.y,c1.z,c1.w, c2.x,c2.y,c2.z,c2.w};
    #pragma unroll
    for (int h = 0; h < HH; ++h) {
      acc[h].x = fmaf(w[h], pv.x, acc[h].x);
      acc[h].y = fmaf(w[h], pv.y, acc[h].y);
      acc[h].z = fmaf(w[h], pv.z, acc[h].z);
      acc[h].w = fmaf(w[h], pv.w, acc[h].w);
    }
  }
  #pragma unroll
  for (int h = 0; h < HH; ++h) sRed[bg][h][c4] = acc[h];
  __syncthreads();
  for (int s = 4; s >= 1; s >>= 1) {
    if (bg < s) {
      #pragma unroll
      for (int h = 0; h < HH; ++h) {
        float4 a = sRed[bg][h][c4], b2 = sRed[bg+s][h][c4];
        a.x+=b2.x; a.y+=b2.y; a.z+=b2.z; a.w+=b2.w;
        sRed[bg][h][c4] = a;
      }
    }
    __syncthreads();
  }
  if (bg == 0) {
    size_t base = (size_t)i*ATT_COLS + 192;
    #pragma unroll
    for (int h = 0; h < HH; ++h)
      *reinterpret_cast<float4*>(att + base + h*Cn + c4*4) = sRed[0][h][c4];
  }
}

// ---------------------------------------------------------------------------
// Kernel D: out = att @ Wout + b_out.  grid (128, 2): 4 rows/block, j-split 2.
// att rows read with uniform (scalar) loads; Wout coalesced over s.
// ---------------------------------------------------------------------------
__global__ __launch_bounds__(384) void ipa_out(
    const float* __restrict__ att, const float* __restrict__ Wout,
    const float* __restrict__ b_out, float* __restrict__ out)
{
  const int n0 = blockIdx.x * 4;
  const int jbase = blockIdx.y * (ATT_COLS/2);
  const int s = threadIdx.x;
  float a0=0.f,a1=0.f,a2=0.f,a3=0.f;
  for (int j = jbase; j < jbase + ATT_COLS/2; j += 4) {
    float4 av0 = *reinterpret_cast<const float4*>(att + (size_t)(n0+0)*ATT_COLS + j);
    float4 av1 = *reinterpret_cast<const float4*>(att + (size_t)(n0+1)*ATT_COLS + j);
    float4 av2 = *reinterpret_cast<const float4*>(att + (size_t)(n0+2)*ATT_COLS + j);
    float4 av3 = *reinterpret_cast<const float4*>(att + (size_t)(n0+3)*ATT_COLS + j);
    float r0[4] = {av0.x,av0.y,av0.z,av0.w};
    float r1[4] = {av1.x,av1.y,av1.z,av1.w};
    float r2[4] = {av2.x,av2.y,av2.z,av2.w};
    float r3[4] = {av3.x,av3.y,av3.z,av3.w};
    #pragma unroll
    for (int jj = 0; jj < 4; ++jj) {
      float wv = Wout[(size_t)(j+jj)*Sn + s];
      a0 = fmaf(r0[jj], wv, a0);
      a1 = fmaf(r1[jj], wv, a1);
      a2 = fmaf(r2[jj], wv, a2);
      a3 = fmaf(r3[jj], wv, a3);
    }
  }
  if (blockIdx.y == 0) {
    float bb = b_out[s];
    a0 += bb; a1 += bb; a2 += bb; a3 += bb;
  }
  atomicAdd(&out[(size_t)(n0+0)*Sn + s], a0);
  atomicAdd(&out[(size_t)(n0+1)*Sn + s], a1);
  atomicAdd(&out[(size_t)(n0+2)*Sn + s], a2);
  atomicAdd(&out[(size_t)(n0+3)*Sn + s], a3);
}

// ---------------------------------------------------------------------------
extern "C" void kernel_launch(void* const* d_in, const int* in_sizes, int n_in,
                              void* d_out, int out_size, void* d_ws, size_t ws_size,
                              hipStream_t stream) {
  const float* single = (const float*)d_in[0];
  const float* pair   = (const float*)d_in[1];
  const float* Rm     = (const float*)d_in[2];
  const float* tr     = (const float*)d_in[3];
  const float* Wq     = (const float*)d_in[4];
  const float* Wk     = (const float*)d_in[5];
  const float* Wv     = (const float*)d_in[6];
  const float* Wqp    = (const float*)d_in[7];
  const float* Wkp    = (const float*)d_in[8];
  const float* Wvp    = (const float*)d_in[9];
  const float* Wb     = (const float*)d_in[10];
  const float* Wout   = (const float*)d_in[11];
  const float* b_out  = (const float*)d_in[12];
  const float* scale_head = (const float*)d_in[13];
  float* ws  = (float*)d_ws;
  float* out = (float*)d_out;

  hipMemsetAsync(ws + OFF_CS, 0, NRES*HH*sizeof(float), stream);
  hipMemsetAsync(out, 0, (size_t)NRES*Sn*sizeof(float), stream);
  ipa_proj<<<dim3(64, 8), 256, 0, stream>>>(single, Rm, tr, Wq, Wk, Wv, Wqp, Wkp, Wvp, ws);
  ipa_attn<<<dim3(NRES), 256, 0, stream>>>(pair, Wb, scale_head, Rm, tr, ws);
  ipa_pairagg<<<dim3(NRES), 256, 0, stream>>>(pair, ws);
  ipa_out<<<dim3(128, 2), 384, 0, stream>>>(ws + OFF_ATT, Wout, b_out, out);
}

// Round 2
// 457.736 us; speedup vs baseline: 1.1122x; 1.1122x over previous
//
#include <hip/hip_runtime.h>
#include <math.h>

#define NRES 512
#define HH 12
#define PQn 4
#define PVn 8
#define En 16
#define Cn 128
#define Sn 384
#define ATT_COLS 2112   // 192 att_single | 1536 att_pair | 288 points | 96 norms

// workspace float offsets
#define OFF_Q    0
#define OFF_K    (OFF_Q   + HH*NRES*En)
#define OFF_V    (OFF_K   + HH*NRES*En)
#define OFF_LQP  (OFF_V   + HH*NRES*En)
#define OFF_LKP  (OFF_LQP + HH*NRES*12)
#define OFF_LVP  (OFF_LKP + HH*NRES*12)
#define OFF_CS   (OFF_LVP + HH*NRES*24)     // colsum [H][N]
#define OFF_ATT  (OFF_CS  + NRES*HH)        // att [NRES][ATT_COLS]
#define OFF_LG   (OFF_ATT + NRES*ATT_COLS)  // logits/weights [H][N][N]  (12.6 MB)

// ---------------------------------------------------------------------------
// Kernel A: projections q/k/v and point projections with frame application.
// ---------------------------------------------------------------------------
__global__ __launch_bounds__(256) void ipa_proj(
    const float* __restrict__ single, const float* __restrict__ Rm,
    const float* __restrict__ tr,
    const float* __restrict__ Wq, const float* __restrict__ Wk,
    const float* __restrict__ Wv, const float* __restrict__ Wqp,
    const float* __restrict__ Wkp, const float* __restrict__ Wvp,
    float* __restrict__ ws)
{
  float* q   = ws + OFF_Q;  float* k   = ws + OFF_K;  float* v   = ws + OFF_V;
  float* lqp = ws + OFF_LQP; float* lkp = ws + OFF_LKP; float* lvp = ws + OFF_LVP;
  const int n0 = blockIdx.x * 8;
  const int g  = blockIdx.y;
  const int tid = threadIdx.x;
  __shared__ float sS[8][388];
  __shared__ float sR[8][9];
  __shared__ float sT[8][3];
  #pragma unroll
  for (int i = 0; i < 3; ++i) {
    int idx = i*256 + tid;
    int r = idx / 96, c4 = idx % 96;
    float4 val = *reinterpret_cast<const float4*>(single + (size_t)(n0 + r)*Sn + c4*4);
    *reinterpret_cast<float4*>(&sS[r][c4*4]) = val;
  }
  if (tid < 72)      sR[tid/9][tid%9] = Rm[(size_t)(n0 + tid/9)*9 + tid%9];
  else if (tid < 96) { int r = (tid-72)/3; sT[r][(tid-72)%3] = tr[(size_t)(n0+r)*3 + (tid-72)%3]; }
  __syncthreads();
  #pragma unroll
  for (int i = 0; i < 3; ++i) {
    int item = i*256 + tid;
    int nl = item & 7;
    int ul = item >> 3;
    int u  = g*96 + ul;
    const float* srow = sS[nl];
    if (u < 576) {
      int which = u/192, r = u%192, h = r>>4, e = r&15;
      const float* W = (which==0 ? Wq : which==1 ? Wk : Wv) + (size_t)h*Sn*En + e;
      float acc = 0.f;
      #pragma unroll 8
      for (int d = 0; d < Sn; ++d) acc = fmaf(srow[d], W[(size_t)d*En], acc);
      float* dst = (which==0 ? q : which==1 ? k : v);
      dst[((size_t)h*NRES + (n0+nl))*En + e] = acc;
    } else {
      int u2 = u - 576;
      const float* W; float* dst;
      if (u2 < 48)      { int h=u2>>2,     p=u2&3;      W = Wqp + (size_t)(h*PQn+p)*Sn*3; dst = lqp + ((size_t)h*NRES + (n0+nl))*12 + p*3; }
      else if (u2 < 96) { int h=(u2-48)>>2,p=(u2-48)&3; W = Wkp + (size_t)(h*PQn+p)*Sn*3; dst = lkp + ((size_t)h*NRES + (n0+nl))*12 + p*3; }
      else              { int h=(u2-96)>>3,p=(u2-96)&7; W = Wvp + (size_t)(h*PVn+p)*Sn*3; dst = lvp + ((size_t)h*NRES + (n0+nl))*24 + p*3; }
      float x0=0.f,x1=0.f,x2=0.f;
      #pragma unroll 4
      for (int d = 0; d < Sn; ++d) {
        float sv = srow[d];
        x0 = fmaf(sv, W[d*3+0], x0);
        x1 = fmaf(sv, W[d*3+1], x1);
        x2 = fmaf(sv, W[d*3+2], x2);
      }
      const float* R8 = sR[nl]; const float* T8 = sT[nl];
      dst[0] = R8[0]*x0 + R8[1]*x1 + R8[2]*x2 + T8[0];
      dst[1] = R8[3]*x0 + R8[4]*x1 + R8[5]*x2 + T8[1];
      dst[2] = R8[6]*x0 + R8[7]*x1 + R8[8]*x2 + T8[2];
    }
  }
}

// ---------------------------------------------------------------------------
// Kernel B: logits[h][n][m] = pair-bias + qk + frame. grid (512 n, 8 m-tiles).
// Each block stages one 64x128 pair tile (XOR-swizzled, conflict-free).
// Wave w handles heads 3w..3w+2, lane = m within tile.
// ---------------------------------------------------------------------------
__global__ __launch_bounds__(256) void ipa_logits(
    const float* __restrict__ pair, const float* __restrict__ Wb,
    const float* __restrict__ scale_head, float* __restrict__ ws)
{
  const float* q   = ws + OFF_Q;  const float* k   = ws + OFF_K;
  const float* lqp = ws + OFF_LQP; const float* lkp = ws + OFF_LKP;
  float* lg = ws + OFF_LG;
  const int n  = blockIdx.x;
  const int mt = blockIdx.y;
  const int tid = threadIdx.x;
  const int lane = tid & 63;
  const int wave = tid >> 6;
  const int h0 = wave*3;
  const int m0 = mt*64;

  __shared__ float tile[64*128];
  const float* src = pair + ((size_t)n*NRES + m0)*Cn;
  #pragma unroll
  for (int i = 0; i < 8; ++i) {
    int idx = i*256 + tid;           // 0..2047 float4 units
    int r = idx >> 5, cf = idx & 31;
    float4 val = *reinterpret_cast<const float4*>(src + (size_t)r*Cn + cf*4);
    *reinterpret_cast<float4*>(&tile[r*128 + ((cf ^ (r & 31)) << 2)]) = val;
  }
  __syncthreads();

  float p[3] = {0.f, 0.f, 0.f};
  #pragma unroll 8
  for (int c4 = 0; c4 < 32; ++c4) {
    float4 pv = *reinterpret_cast<const float4*>(&tile[lane*128 + ((c4 ^ (lane & 31)) << 2)]);
    float4 w0 = *reinterpret_cast<const float4*>(Wb + (h0+0)*Cn + c4*4);
    float4 w1 = *reinterpret_cast<const float4*>(Wb + (h0+1)*Cn + c4*4);
    float4 w2 = *reinterpret_cast<const float4*>(Wb + (h0+2)*Cn + c4*4);
    p[0] += pv.x*w0.x + pv.y*w0.y + pv.z*w0.z + pv.w*w0.w;
    p[1] += pv.x*w1.x + pv.y*w1.y + pv.z*w1.z + pv.w*w1.w;
    p[2] += pv.x*w2.x + pv.y*w2.y + pv.z*w2.z + pv.w*w2.w;
  }

  const int m = m0 + lane;
  #pragma unroll
  for (int i = 0; i < 3; ++i) {
    const int h = h0 + i;
    const float* qh = q + ((size_t)h*NRES + n)*En;   // uniform
    const float* kh = k + ((size_t)h*NRES + m)*En;
    float qk = 0.f;
    #pragma unroll
    for (int e = 0; e < En; ++e) qk = fmaf(qh[e], kh[e], qk);
    const float* lq = lqp + ((size_t)h*NRES + n)*12; // uniform
    const float* lk = lkp + ((size_t)h*NRES + m)*12;
    float cross=0.f, Bm=0.f, An=0.f;
    #pragma unroll
    for (int jj = 0; jj < 12; ++jj) {
      float a = lq[jj], b = lk[jj];
      cross = fmaf(a, b, cross); Bm = fmaf(b, b, Bm); An = fmaf(a, a, An);
    }
    float gamma = 0.11785113019775793f * log1pf(__expf(scale_head[h]));
    lg[((size_t)h*NRES + n)*NRES + m] = p[i] + 0.25f*qk - gamma*(An + Bm - 2.f*cross);
  }
}

// ---------------------------------------------------------------------------
// Kernel C: softmax in place over last axis of lg[H][N][N]. One wave per row.
// ---------------------------------------------------------------------------
__global__ __launch_bounds__(256) void ipa_softmax(float* __restrict__ ws)
{
  float* lg = ws + OFF_LG;
  const int row  = blockIdx.x*4 + (threadIdx.x >> 6);  // h*N + n
  const int lane = threadIdx.x & 63;
  float4* p = reinterpret_cast<float4*>(lg + (size_t)row*NRES);
  float4 x0 = p[lane];
  float4 x1 = p[64 + lane];
  float mx = fmaxf(fmaxf(fmaxf(x0.x,x0.y),fmaxf(x0.z,x0.w)),
                   fmaxf(fmaxf(x1.x,x1.y),fmaxf(x1.z,x1.w)));
  #pragma unroll
  for (int off = 32; off >= 1; off >>= 1) mx = fmaxf(mx, __shfl_xor(mx, off));
  x0.x = __expf(x0.x-mx); x0.y = __expf(x0.y-mx); x0.z = __expf(x0.z-mx); x0.w = __expf(x0.w-mx);
  x1.x = __expf(x1.x-mx); x1.y = __expf(x1.y-mx); x1.z = __expf(x1.z-mx); x1.w = __expf(x1.w-mx);
  float sum = x0.x+x0.y+x0.z+x0.w + x1.x+x1.y+x1.z+x1.w;
  #pragma unroll
  for (int off = 32; off >= 1; off >>= 1) sum += __shfl_xor(sum, off);
  const float inv = 1.f/sum;
  x0.x*=inv; x0.y*=inv; x0.z*=inv; x0.w*=inv;
  x1.x*=inv; x1.y*=inv; x1.z*=inv; x1.w*=inv;
  p[lane] = x0;
  p[64 + lane] = x1;
}

// ---------------------------------------------------------------------------
// Kernel D: colsum[h][b] = sum_a w[h][a][b]. grid (12, 8 a-chunks).
// ---------------------------------------------------------------------------
__global__ __launch_bounds__(256) void ipa_colsum(float* __restrict__ ws)
{
  const float* lg = ws + OFF_LG;
  float* cs = ws + OFF_CS;
  const int h = blockIdx.x, ac = blockIdx.y, tid = threadIdx.x;
  const float* base = lg + (size_t)h*NRES*NRES + (size_t)ac*64*NRES;
  float acc0 = 0.f, acc1 = 0.f;
  #pragma unroll 4
  for (int a = 0; a < 64; ++a) {
    acc0 += base[(size_t)a*NRES + tid];
    acc1 += base[(size_t)a*NRES + tid + 256];
  }
  atomicAdd(&cs[h*NRES + tid],       acc0);
  atomicAdd(&cs[h*NRES + tid + 256], acc1);
}

// ---------------------------------------------------------------------------
// Kernel E: att_single = w.v, local_out = w.lvp, inverse frame + norms.
// One wave per (h,n) row; v/lvp are L2-resident (960 KB).
// ---------------------------------------------------------------------------
__global__ __launch_bounds__(256) void ipa_agg(
    const float* __restrict__ Rm, const float* __restrict__ tr,
    float* __restrict__ ws)
{
  const float* v   = ws + OFF_V;
  const float* lvp = ws + OFF_LVP;
  const float* lg  = ws + OFF_LG;
  float* att = ws + OFF_ATT;
  const int row  = blockIdx.x*4 + (threadIdx.x >> 6);  // h*N + n
  const int lane = threadIdx.x & 63;
  const int h = row >> 9, n = row & 511;

  float acc[40];
  #pragma unroll
  for (int i = 0; i < 40; ++i) acc[i] = 0.f;

  const float* wrow = lg + (size_t)row*NRES;
  #pragma unroll 2
  for (int j = 0; j < 8; ++j) {
    const int m = j*64 + lane;
    const float wv = wrow[m];
    const float4* v4 = reinterpret_cast<const float4*>(v + ((size_t)h*NRES + m)*En);
    float4 a0=v4[0], a1=v4[1], a2=v4[2], a3=v4[3];
    acc[0]+=wv*a0.x; acc[1]+=wv*a0.y; acc[2]+=wv*a0.z; acc[3]+=wv*a0.w;
    acc[4]+=wv*a1.x; acc[5]+=wv*a1.y; acc[6]+=wv*a1.z; acc[7]+=wv*a1.w;
    acc[8]+=wv*a2.x; acc[9]+=wv*a2.y; acc[10]+=wv*a2.z; acc[11]+=wv*a2.w;
    acc[12]+=wv*a3.x; acc[13]+=wv*a3.y; acc[14]+=wv*a3.z; acc[15]+=wv*a3.w;
    const float4* l4 = reinterpret_cast<const float4*>(lvp + ((size_t)h*NRES + m)*24);
    #pragma unroll
    for (int t = 0; t < 6; ++t) {
      float4 b = l4[t];
      acc[16+4*t+0]+=wv*b.x; acc[16+4*t+1]+=wv*b.y;
      acc[16+4*t+2]+=wv*b.z; acc[16+4*t+3]+=wv*b.w;
    }
  }
  #pragma unroll
  for (int off = 32; off >= 1; off >>= 1) {
    #pragma unroll
    for (int i = 0; i < 40; ++i) acc[i] += __shfl_xor(acc[i], off);
  }
  if (lane == 0) {
    size_t ab = (size_t)n*ATT_COLS;
    float4* as = reinterpret_cast<float4*>(att + ab + h*En);
    as[0] = make_float4(acc[0],acc[1],acc[2],acc[3]);
    as[1] = make_float4(acc[4],acc[5],acc[6],acc[7]);
    as[2] = make_float4(acc[8],acc[9],acc[10],acc[11]);
    as[3] = make_float4(acc[12],acc[13],acc[14],acc[15]);
    const float R0=Rm[n*9+0],R1=Rm[n*9+1],R2=Rm[n*9+2],
                R3=Rm[n*9+3],R4=Rm[n*9+4],R5=Rm[n*9+5],
                R6=Rm[n*9+6],R7=Rm[n*9+7],R8=Rm[n*9+8];
    const float t0=tr[n*3+0], t1=tr[n*3+1], t2=tr[n*3+2];
    #pragma unroll
    for (int pp = 0; pp < 8; ++pp) {
      float d0 = acc[16+3*pp+0]-t0, d1 = acc[16+3*pp+1]-t1, d2 = acc[16+3*pp+2]-t2;
      float g0 = R0*d0 + R3*d1 + R6*d2;
      float g1 = R1*d0 + R4*d1 + R7*d2;
      float g2 = R2*d0 + R5*d1 + R8*d2;
      att[ab + 1728 + (pp*HH + h)*3 + 0] = g0;
      att[ab + 1728 + (pp*HH + h)*3 + 1] = g1;
      att[ab + 1728 + (pp*HH + h)*3 + 2] = g2;
      att[ab + 2016 + pp*HH + h] = sqrtf(g0*g0 + g1*g1 + g2*g2);
    }
  }
}

// ---------------------------------------------------------------------------
// Kernel F: att_pair[h,i,c] = sum_b colsum[h,b]*pair[i,b,c]. One block per i.
// ---------------------------------------------------------------------------
__global__ __launch_bounds__(256) void ipa_pairagg(
    const float* __restrict__ pair, float* __restrict__ ws)
{
  const float* cs = ws + OFF_CS;     // [H][N]
  float* att = ws + OFF_ATT;
  const int i = blockIdx.x, tid = threadIdx.x;
  __shared__ float sCS[HH*NRES];
  __shared__ float4 sRed[8][HH][32];
  #pragma unroll
  for (int it = 0; it < 6; ++it) {
    int idx = it*256 + tid;
    reinterpret_cast<float4*>(sCS)[idx] = reinterpret_cast<const float4*>(cs)[idx];
  }
  __syncthreads();
  const int c4 = tid & 31, bg = tid >> 5;
  float4 acc[HH];
  #pragma unroll
  for (int h = 0; h < HH; ++h) acc[h] = make_float4(0.f,0.f,0.f,0.f);
  const float* prow = pair + (size_t)i*NRES*Cn;
  for (int b = bg; b < NRES; b += 8) {
    float4 pv = *reinterpret_cast<const float4*>(prow + (size_t)b*Cn + c4*4);
    #pragma unroll
    for (int h = 0; h < HH; ++h) {
      float w = sCS[h*NRES + b];
      acc[h].x = fmaf(w, pv.x, acc[h].x);
      acc[h].y = fmaf(w, pv.y, acc[h].y);
      acc[h].z = fmaf(w, pv.z, acc[h].z);
      acc[h].w = fmaf(w, pv.w, acc[h].w);
    }
  }
  #pragma unroll
  for (int h = 0; h < HH; ++h) sRed[bg][h][c4] = acc[h];
  __syncthreads();
  for (int s = 4; s >= 1; s >>= 1) {
    if (bg < s) {
      #pragma unroll
      for (int h = 0; h < HH; ++h) {
        float4 a = sRed[bg][h][c4], b2 = sRed[bg+s][h][c4];
        a.x+=b2.x; a.y+=b2.y; a.z+=b2.z; a.w+=b2.w;
        sRed[bg][h][c4] = a;
      }
    }
    __syncthreads();
  }
  if (bg == 0) {
    size_t base = (size_t)i*ATT_COLS + 192;
    #pragma unroll
    for (int h = 0; h < HH; ++h)
      *reinterpret_cast<float4*>(att + base + h*Cn + c4*4) = sRed[0][h][c4];
  }
}

// ---------------------------------------------------------------------------
// Kernel G: out = att @ Wout + b_out. grid (32, 2): 16 rows/block, j-split 2.
// ---------------------------------------------------------------------------
__global__ __launch_bounds__(384) void ipa_out(
    const float* __restrict__ att, const float* __restrict__ Wout,
    const float* __restrict__ b_out, float* __restrict__ out)
{
  const int n0 = blockIdx.x * 16;
  const int jbase = blockIdx.y * (ATT_COLS/2);
  const int s = threadIdx.x;
  float a[16];
  #pragma unroll
  for (int r = 0; r < 16; ++r) a[r] = 0.f;
  for (int j = jbase; j < jbase + ATT_COLS/2; j += 4) {
    float w0 = Wout[(size_t)(j+0)*Sn + s];
    float w1 = Wout[(size_t)(j+1)*Sn + s];
    float w2 = Wout[(size_t)(j+2)*Sn + s];
    float w3 = Wout[(size_t)(j+3)*Sn + s];
    #pragma unroll
    for (int r = 0; r < 16; ++r) {
      float4 av = *reinterpret_cast<const float4*>(att + (size_t)(n0+r)*ATT_COLS + j);
      a[r] = fmaf(av.x, w0, a[r]);
      a[r] = fmaf(av.y, w1, a[r]);
      a[r] = fmaf(av.z, w2, a[r]);
      a[r] = fmaf(av.w, w3, a[r]);
    }
  }
  if (blockIdx.y == 0) {
    float bb = b_out[s];
    #pragma unroll
    for (int r = 0; r < 16; ++r) a[r] += bb;
  }
  #pragma unroll
  for (int r = 0; r < 16; ++r)
    atomicAdd(&out[(size_t)(n0+r)*Sn + s], a[r]);
}

// ---------------------------------------------------------------------------
extern "C" void kernel_launch(void* const* d_in, const int* in_sizes, int n_in,
                              void* d_out, int out_size, void* d_ws, size_t ws_size,
                              hipStream_t stream) {
  const float* single = (const float*)d_in[0];
  const float* pair   = (const float*)d_in[1];
  const float* Rm     = (const float*)d_in[2];
  const float* tr     = (const float*)d_in[3];
  const float* Wq     = (const float*)d_in[4];
  const float* Wk     = (const float*)d_in[5];
  const float* Wv     = (const float*)d_in[6];
  const float* Wqp    = (const float*)d_in[7];
  const float* Wkp    = (const float*)d_in[8];
  const float* Wvp    = (const float*)d_in[9];
  const float* Wb     = (const float*)d_in[10];
  const float* Wout   = (const float*)d_in[11];
  const float* b_out  = (const float*)d_in[12];
  const float* scale_head = (const float*)d_in[13];
  float* ws  = (float*)d_ws;
  float* out = (float*)d_out;

  hipMemsetAsync(ws + OFF_CS, 0, NRES*HH*sizeof(float), stream);
  hipMemsetAsync(out, 0, (size_t)NRES*Sn*sizeof(float), stream);
  ipa_proj   <<<dim3(64, 8),  256, 0, stream>>>(single, Rm, tr, Wq, Wk, Wv, Wqp, Wkp, Wvp, ws);
  ipa_logits <<<dim3(NRES, 8),256, 0, stream>>>(pair, Wb, scale_head, ws);
  ipa_softmax<<<dim3(HH*NRES/4), 256, 0, stream>>>(ws);
  ipa_colsum <<<dim3(HH, 8),  256, 0, stream>>>(ws);
  ipa_agg    <<<dim3(HH*NRES/4), 256, 0, stream>>>(Rm, tr, ws);
  ipa_pairagg<<<dim3(NRES),   256, 0, stream>>>(pair, ws);
  ipa_out    <<<dim3(32, 2),  384, 0, stream>>>(ws + OFF_ATT, Wout, b_out, out);
}

// Round 3
// 345.228 us; speedup vs baseline: 1.4747x; 1.3259x over previous
//
#include <hip/hip_runtime.h>
#include <math.h>

#define NRES 512
#define HH 12
#define PQn 4
#define PVn 8
#define En 16
#define Cn 128
#define Sn 384
#define ATT_COLS 2112   // 192 att_single | 1536 att_pair | 288 points | 96 norms

// workspace float offsets
#define OFF_Q    0
#define OFF_K    (OFF_Q   + HH*NRES*En)
#define OFF_V    (OFF_K   + HH*NRES*En)
#define OFF_LQP  (OFF_V   + HH*NRES*En)
#define OFF_LKP  (OFF_LQP + HH*NRES*12)
#define OFF_LVP  (OFF_LKP + HH*NRES*12)
#define OFF_CS   (OFF_LVP + HH*NRES*24)     // colsum [H][N]
#define OFF_ATT  (OFF_CS  + NRES*HH)        // att [NRES][ATT_COLS]
#define OFF_LG   (OFF_ATT + NRES*ATT_COLS)  // logits/weights [H][N][N] (12.6 MB)
// out-GEMM partial buffer aliases LG (lg dead by then; both 3,145,728 floats)
#define OFF_PART OFF_LG
#define KSPLIT 16
#define KCHUNK (ATT_COLS/KSPLIT)   // 132

// ---------------------------------------------------------------------------
// Kernel A: projections q/k/v and point projections with frame application.
// ---------------------------------------------------------------------------
__global__ __launch_bounds__(256) void ipa_proj(
    const float* __restrict__ single, const float* __restrict__ Rm,
    const float* __restrict__ tr,
    const float* __restrict__ Wq, const float* __restrict__ Wk,
    const float* __restrict__ Wv, const float* __restrict__ Wqp,
    const float* __restrict__ Wkp, const float* __restrict__ Wvp,
    float* __restrict__ ws)
{
  float* q   = ws + OFF_Q;  float* k   = ws + OFF_K;  float* v   = ws + OFF_V;
  float* lqp = ws + OFF_LQP; float* lkp = ws + OFF_LKP; float* lvp = ws + OFF_LVP;
  const int n0 = blockIdx.x * 8;
  const int g  = blockIdx.y;
  const int tid = threadIdx.x;
  __shared__ float sS[8][388];
  __shared__ float sR[8][9];
  __shared__ float sT[8][3];
  #pragma unroll
  for (int i = 0; i < 3; ++i) {
    int idx = i*256 + tid;
    int r = idx / 96, c4 = idx % 96;
    float4 val = *reinterpret_cast<const float4*>(single + (size_t)(n0 + r)*Sn + c4*4);
    *reinterpret_cast<float4*>(&sS[r][c4*4]) = val;
  }
  if (tid < 72)      sR[tid/9][tid%9] = Rm[(size_t)(n0 + tid/9)*9 + tid%9];
  else if (tid < 96) { int r = (tid-72)/3; sT[r][(tid-72)%3] = tr[(size_t)(n0+r)*3 + (tid-72)%3]; }
  __syncthreads();
  #pragma unroll
  for (int i = 0; i < 3; ++i) {
    int item = i*256 + tid;
    int nl = item & 7;
    int ul = item >> 3;
    int u  = g*96 + ul;
    const float* srow = sS[nl];
    if (u < 576) {
      int which = u/192, r = u%192, h = r>>4, e = r&15;
      const float* W = (which==0 ? Wq : which==1 ? Wk : Wv) + (size_t)h*Sn*En + e;
      float acc = 0.f;
      #pragma unroll 8
      for (int d = 0; d < Sn; ++d) acc = fmaf(srow[d], W[(size_t)d*En], acc);
      float* dst = (which==0 ? q : which==1 ? k : v);
      dst[((size_t)h*NRES + (n0+nl))*En + e] = acc;
    } else {
      int u2 = u - 576;
      const float* W; float* dst;
      if (u2 < 48)      { int h=u2>>2,     p=u2&3;      W = Wqp + (size_t)(h*PQn+p)*Sn*3; dst = lqp + ((size_t)h*NRES + (n0+nl))*12 + p*3; }
      else if (u2 < 96) { int h=(u2-48)>>2,p=(u2-48)&3; W = Wkp + (size_t)(h*PQn+p)*Sn*3; dst = lkp + ((size_t)h*NRES + (n0+nl))*12 + p*3; }
      else              { int h=(u2-96)>>3,p=(u2-96)&7; W = Wvp + (size_t)(h*PVn+p)*Sn*3; dst = lvp + ((size_t)h*NRES + (n0+nl))*24 + p*3; }
      float x0=0.f,x1=0.f,x2=0.f;
      #pragma unroll 4
      for (int d = 0; d < Sn; ++d) {
        float sv = srow[d];
        x0 = fmaf(sv, W[d*3+0], x0);
        x1 = fmaf(sv, W[d*3+1], x1);
        x2 = fmaf(sv, W[d*3+2], x2);
      }
      const float* R8 = sR[nl]; const float* T8 = sT[nl];
      dst[0] = R8[0]*x0 + R8[1]*x1 + R8[2]*x2 + T8[0];
      dst[1] = R8[3]*x0 + R8[4]*x1 + R8[5]*x2 + T8[1];
      dst[2] = R8[6]*x0 + R8[7]*x1 + R8[8]*x2 + T8[2];
    }
  }
}

// ---------------------------------------------------------------------------
// Kernel B: logits[h][n][m] = pair-bias + qk + frame. grid (512 n, 8 m-tiles).
// ---------------------------------------------------------------------------
__global__ __launch_bounds__(256) void ipa_logits(
    const float* __restrict__ pair, const float* __restrict__ Wb,
    const float* __restrict__ scale_head, float* __restrict__ ws)
{
  const float* q   = ws + OFF_Q;  const float* k   = ws + OFF_K;
  const float* lqp = ws + OFF_LQP; const float* lkp = ws + OFF_LKP;
  float* lg = ws + OFF_LG;
  const int n  = blockIdx.x;
  const int mt = blockIdx.y;
  const int tid = threadIdx.x;
  const int lane = tid & 63;
  const int wave = tid >> 6;
  const int h0 = wave*3;
  const int m0 = mt*64;

  __shared__ float tile[64*128];
  const float* src = pair + ((size_t)n*NRES + m0)*Cn;
  #pragma unroll
  for (int i = 0; i < 8; ++i) {
    int idx = i*256 + tid;
    int r = idx >> 5, cf = idx & 31;
    float4 val = *reinterpret_cast<const float4*>(src + (size_t)r*Cn + cf*4);
    *reinterpret_cast<float4*>(&tile[r*128 + ((cf ^ (r & 31)) << 2)]) = val;
  }
  __syncthreads();

  float p[3] = {0.f, 0.f, 0.f};
  #pragma unroll 8
  for (int c4 = 0; c4 < 32; ++c4) {
    float4 pv = *reinterpret_cast<const float4*>(&tile[lane*128 + ((c4 ^ (lane & 31)) << 2)]);
    float4 w0 = *reinterpret_cast<const float4*>(Wb + (h0+0)*Cn + c4*4);
    float4 w1 = *reinterpret_cast<const float4*>(Wb + (h0+1)*Cn + c4*4);
    float4 w2 = *reinterpret_cast<const float4*>(Wb + (h0+2)*Cn + c4*4);
    p[0] += pv.x*w0.x + pv.y*w0.y + pv.z*w0.z + pv.w*w0.w;
    p[1] += pv.x*w1.x + pv.y*w1.y + pv.z*w1.z + pv.w*w1.w;
    p[2] += pv.x*w2.x + pv.y*w2.y + pv.z*w2.z + pv.w*w2.w;
  }

  const int m = m0 + lane;
  #pragma unroll
  for (int i = 0; i < 3; ++i) {
    const int h = h0 + i;
    const float* qh = q + ((size_t)h*NRES + n)*En;
    const float* kh = k + ((size_t)h*NRES + m)*En;
    float qk = 0.f;
    #pragma unroll
    for (int e = 0; e < En; ++e) qk = fmaf(qh[e], kh[e], qk);
    const float* lq = lqp + ((size_t)h*NRES + n)*12;
    const float* lk = lkp + ((size_t)h*NRES + m)*12;
    float cross=0.f, Bm=0.f, An=0.f;
    #pragma unroll
    for (int jj = 0; jj < 12; ++jj) {
      float a = lq[jj], b = lk[jj];
      cross = fmaf(a, b, cross); Bm = fmaf(b, b, Bm); An = fmaf(a, a, An);
    }
    float gamma = 0.11785113019775793f * log1pf(__expf(scale_head[h]));
    lg[((size_t)h*NRES + n)*NRES + m] = p[i] + 0.25f*qk - gamma*(An + Bm - 2.f*cross);
  }
}

// ---------------------------------------------------------------------------
// Kernel C: softmax in place over last axis of lg[H][N][N]. One wave per row.
// ---------------------------------------------------------------------------
__global__ __launch_bounds__(256) void ipa_softmax(float* __restrict__ ws)
{
  float* lg = ws + OFF_LG;
  const int row  = blockIdx.x*4 + (threadIdx.x >> 6);
  const int lane = threadIdx.x & 63;
  float4* p = reinterpret_cast<float4*>(lg + (size_t)row*NRES);
  float4 x0 = p[lane];
  float4 x1 = p[64 + lane];
  float mx = fmaxf(fmaxf(fmaxf(x0.x,x0.y),fmaxf(x0.z,x0.w)),
                   fmaxf(fmaxf(x1.x,x1.y),fmaxf(x1.z,x1.w)));
  #pragma unroll
  for (int off = 32; off >= 1; off >>= 1) mx = fmaxf(mx, __shfl_xor(mx, off));
  x0.x = __expf(x0.x-mx); x0.y = __expf(x0.y-mx); x0.z = __expf(x0.z-mx); x0.w = __expf(x0.w-mx);
  x1.x = __expf(x1.x-mx); x1.y = __expf(x1.y-mx); x1.z = __expf(x1.z-mx); x1.w = __expf(x1.w-mx);
  float sum = x0.x+x0.y+x0.z+x0.w + x1.x+x1.y+x1.z+x1.w;
  #pragma unroll
  for (int off = 32; off >= 1; off >>= 1) sum += __shfl_xor(sum, off);
  const float inv = 1.f/sum;
  x0.x*=inv; x0.y*=inv; x0.z*=inv; x0.w*=inv;
  x1.x*=inv; x1.y*=inv; x1.z*=inv; x1.w*=inv;
  p[lane] = x0;
  p[64 + lane] = x1;
}

// ---------------------------------------------------------------------------
// Kernel D: colsum[h][b] = sum_a w[h][a][b]. grid (12, 8 a-chunks).
// ---------------------------------------------------------------------------
__global__ __launch_bounds__(256) void ipa_colsum(float* __restrict__ ws)
{
  const float* lg = ws + OFF_LG;
  float* cs = ws + OFF_CS;
  const int h = blockIdx.x, ac = blockIdx.y, tid = threadIdx.x;
  const float* base = lg + (size_t)h*NRES*NRES + (size_t)ac*64*NRES;
  float acc0 = 0.f, acc1 = 0.f;
  #pragma unroll 4
  for (int a = 0; a < 64; ++a) {
    acc0 += base[(size_t)a*NRES + tid];
    acc1 += base[(size_t)a*NRES + tid + 256];
  }
  atomicAdd(&cs[h*NRES + tid],       acc0);
  atomicAdd(&cs[h*NRES + tid + 256], acc1);
}

// ---------------------------------------------------------------------------
// Kernel E: att_single = w.v, local_out = w.lvp, inverse frame + norms.
// ---------------------------------------------------------------------------
__global__ __launch_bounds__(256) void ipa_agg(
    const float* __restrict__ Rm, const float* __restrict__ tr,
    float* __restrict__ ws)
{
  const float* v   = ws + OFF_V;
  const float* lvp = ws + OFF_LVP;
  const float* lg  = ws + OFF_LG;
  float* att = ws + OFF_ATT;
  const int row  = blockIdx.x*4 + (threadIdx.x >> 6);
  const int lane = threadIdx.x & 63;
  const int h = row >> 9, n = row & 511;

  float acc[40];
  #pragma unroll
  for (int i = 0; i < 40; ++i) acc[i] = 0.f;

  const float* wrow = lg + (size_t)row*NRES;
  #pragma unroll 2
  for (int j = 0; j < 8; ++j) {
    const int m = j*64 + lane;
    const float wv = wrow[m];
    const float4* v4 = reinterpret_cast<const float4*>(v + ((size_t)h*NRES + m)*En);
    float4 a0=v4[0], a1=v4[1], a2=v4[2], a3=v4[3];
    acc[0]+=wv*a0.x; acc[1]+=wv*a0.y; acc[2]+=wv*a0.z; acc[3]+=wv*a0.w;
    acc[4]+=wv*a1.x; acc[5]+=wv*a1.y; acc[6]+=wv*a1.z; acc[7]+=wv*a1.w;
    acc[8]+=wv*a2.x; acc[9]+=wv*a2.y; acc[10]+=wv*a2.z; acc[11]+=wv*a2.w;
    acc[12]+=wv*a3.x; acc[13]+=wv*a3.y; acc[14]+=wv*a3.z; acc[15]+=wv*a3.w;
    const float4* l4 = reinterpret_cast<const float4*>(lvp + ((size_t)h*NRES + m)*24);
    #pragma unroll
    for (int t = 0; t < 6; ++t) {
      float4 b = l4[t];
      acc[16+4*t+0]+=wv*b.x; acc[16+4*t+1]+=wv*b.y;
      acc[16+4*t+2]+=wv*b.z; acc[16+4*t+3]+=wv*b.w;
    }
  }
  #pragma unroll
  for (int off = 32; off >= 1; off >>= 1) {
    #pragma unroll
    for (int i = 0; i < 40; ++i) acc[i] += __shfl_xor(acc[i], off);
  }
  if (lane == 0) {
    size_t ab = (size_t)n*ATT_COLS;
    float4* as = reinterpret_cast<float4*>(att + ab + h*En);
    as[0] = make_float4(acc[0],acc[1],acc[2],acc[3]);
    as[1] = make_float4(acc[4],acc[5],acc[6],acc[7]);
    as[2] = make_float4(acc[8],acc[9],acc[10],acc[11]);
    as[3] = make_float4(acc[12],acc[13],acc[14],acc[15]);
    const float R0=Rm[n*9+0],R1=Rm[n*9+1],R2=Rm[n*9+2],
                R3=Rm[n*9+3],R4=Rm[n*9+4],R5=Rm[n*9+5],
                R6=Rm[n*9+6],R7=Rm[n*9+7],R8=Rm[n*9+8];
    const float t0=tr[n*3+0], t1=tr[n*3+1], t2=tr[n*3+2];
    #pragma unroll
    for (int pp = 0; pp < 8; ++pp) {
      float d0 = acc[16+3*pp+0]-t0, d1 = acc[16+3*pp+1]-t1, d2 = acc[16+3*pp+2]-t2;
      float g0 = R0*d0 + R3*d1 + R6*d2;
      float g1 = R1*d0 + R4*d1 + R7*d2;
      float g2 = R2*d0 + R5*d1 + R8*d2;
      att[ab + 1728 + (pp*HH + h)*3 + 0] = g0;
      att[ab + 1728 + (pp*HH + h)*3 + 1] = g1;
      att[ab + 1728 + (pp*HH + h)*3 + 2] = g2;
      att[ab + 2016 + pp*HH + h] = sqrtf(g0*g0 + g1*g1 + g2*g2);
    }
  }
}

// ---------------------------------------------------------------------------
// Kernel F: att_pair[h,i,c] = sum_b colsum[h,b]*pair[i,b,c]. One block per i.
// ---------------------------------------------------------------------------
__global__ __launch_bounds__(256) void ipa_pairagg(
    const float* __restrict__ pair, float* __restrict__ ws)
{
  const float* cs = ws + OFF_CS;
  float* att = ws + OFF_ATT;
  const int i = blockIdx.x, tid = threadIdx.x;
  __shared__ float sCS[HH*NRES];
  __shared__ float4 sRed[8][HH][32];
  #pragma unroll
  for (int it = 0; it < 6; ++it) {
    int idx = it*256 + tid;
    reinterpret_cast<float4*>(sCS)[idx] = reinterpret_cast<const float4*>(cs)[idx];
  }
  __syncthreads();
  const int c4 = tid & 31, bg = tid >> 5;
  float4 acc[HH];
  #pragma unroll
  for (int h = 0; h < HH; ++h) acc[h] = make_float4(0.f,0.f,0.f,0.f);
  const float* prow = pair + (size_t)i*NRES*Cn;
  for (int b = bg; b < NRES; b += 8) {
    float4 pv = *reinterpret_cast<const float4*>(prow + (size_t)b*Cn + c4*4);
    #pragma unroll
    for (int h = 0; h < HH; ++h) {
      float w = sCS[h*NRES + b];
      acc[h].x = fmaf(w, pv.x, acc[h].x);
      acc[h].y = fmaf(w, pv.y, acc[h].y);
      acc[h].z = fmaf(w, pv.z, acc[h].z);
      acc[h].w = fmaf(w, pv.w, acc[h].w);
    }
  }
  #pragma unroll
  for (int h = 0; h < HH; ++h) sRed[bg][h][c4] = acc[h];
  __syncthreads();
  for (int s = 4; s >= 1; s >>= 1) {
    if (bg < s) {
      #pragma unroll
      for (int h = 0; h < HH; ++h) {
        float4 a = sRed[bg][h][c4], b2 = sRed[bg+s][h][c4];
        a.x+=b2.x; a.y+=b2.y; a.z+=b2.z; a.w+=b2.w;
        sRed[bg][h][c4] = a;
      }
    }
    __syncthreads();
  }
  if (bg == 0) {
    size_t base = (size_t)i*ATT_COLS + 192;
    #pragma unroll
    for (int h = 0; h < HH; ++h)
      *reinterpret_cast<float4*>(att + base + h*Cn + c4*4) = sRed[0][h][c4];
  }
}

// ---------------------------------------------------------------------------
// Kernel G1: split-k partial GEMM. grid (16 rowblocks, 16 ksplits), 384 thr.
// Thread owns column s; 32 rows; k-range 132. att loads are thread-uniform
// (scalarized to s_load_dwordx4); Wout loads coalesced; 32 indep FMA chains.
// ---------------------------------------------------------------------------
__global__ __launch_bounds__(384) void ipa_outp(
    const float* __restrict__ att, const float* __restrict__ Wout,
    float* __restrict__ ws)
{
  float* partial = ws + OFF_PART;       // [KSPLIT][NRES][Sn]
  const int rb = blockIdx.x;            // 32 rows each
  const int ks = blockIdx.y;            // 132 k each
  const int s  = threadIdx.x;
  const int n0 = rb*32;
  const int j0 = ks*KCHUNK;

  float acc[32];
  #pragma unroll
  for (int r = 0; r < 32; ++r) acc[r] = 0.f;

  for (int jg = 0; jg < KCHUNK/4; ++jg) {
    const int j = j0 + jg*4;
    float w0 = Wout[(size_t)(j+0)*Sn + s];
    float w1 = Wout[(size_t)(j+1)*Sn + s];
    float w2 = Wout[(size_t)(j+2)*Sn + s];
    float w3 = Wout[(size_t)(j+3)*Sn + s];
    #pragma unroll
    for (int r = 0; r < 32; ++r) {
      float4 av = *reinterpret_cast<const float4*>(att + (size_t)(n0+r)*ATT_COLS + j);
      acc[r] = fmaf(av.x, w0, acc[r]);
      acc[r] = fmaf(av.y, w1, acc[r]);
      acc[r] = fmaf(av.z, w2, acc[r]);
      acc[r] = fmaf(av.w, w3, acc[r]);
    }
  }
  #pragma unroll
  for (int r = 0; r < 32; ++r)
    partial[((size_t)ks*NRES + n0 + r)*Sn + s] = acc[r];
}

// ---------------------------------------------------------------------------
// Kernel G2: out[n][s] = b_out[s] + sum_ks partial[ks][n][s].
// ---------------------------------------------------------------------------
__global__ __launch_bounds__(384) void ipa_outred(
    const float* __restrict__ b_out, float* __restrict__ ws,
    float* __restrict__ out)
{
  const float* partial = ws + OFF_PART;
  const int n = blockIdx.x, s = threadIdx.x;
  float a = b_out[s];
  #pragma unroll
  for (int ks = 0; ks < KSPLIT; ++ks)
    a += partial[((size_t)ks*NRES + n)*Sn + s];
  out[(size_t)n*Sn + s] = a;
}

// ---------------------------------------------------------------------------
extern "C" void kernel_launch(void* const* d_in, const int* in_sizes, int n_in,
                              void* d_out, int out_size, void* d_ws, size_t ws_size,
                              hipStream_t stream) {
  const float* single = (const float*)d_in[0];
  const float* pair   = (const float*)d_in[1];
  const float* Rm     = (const float*)d_in[2];
  const float* tr     = (const float*)d_in[3];
  const float* Wq     = (const float*)d_in[4];
  const float* Wk     = (const float*)d_in[5];
  const float* Wv     = (const float*)d_in[6];
  const float* Wqp    = (const float*)d_in[7];
  const float* Wkp    = (const float*)d_in[8];
  const float* Wvp    = (const float*)d_in[9];
  const float* Wb     = (const float*)d_in[10];
  const float* Wout   = (const float*)d_in[11];
  const float* b_out  = (const float*)d_in[12];
  const float* scale_head = (const float*)d_in[13];
  float* ws  = (float*)d_ws;
  float* out = (float*)d_out;

  hipMemsetAsync(ws + OFF_CS, 0, NRES*HH*sizeof(float), stream);
  ipa_proj   <<<dim3(64, 8),  256, 0, stream>>>(single, Rm, tr, Wq, Wk, Wv, Wqp, Wkp, Wvp, ws);
  ipa_logits <<<dim3(NRES, 8),256, 0, stream>>>(pair, Wb, scale_head, ws);
  ipa_softmax<<<dim3(HH*NRES/4), 256, 0, stream>>>(ws);
  ipa_colsum <<<dim3(HH, 8),  256, 0, stream>>>(ws);
  ipa_agg    <<<dim3(HH*NRES/4), 256, 0, stream>>>(Rm, tr, ws);
  ipa_pairagg<<<dim3(NRES),   256, 0, stream>>>(pair, ws);
  ipa_outp   <<<dim3(16, KSPLIT), 384, 0, stream>>>(ws + OFF_ATT, Wout, ws);
  ipa_outred <<<dim3(NRES),   384, 0, stream>>>(b_out, ws, out);
}

// Round 4
// 271.980 us; speedup vs baseline: 1.8718x; 1.2693x over previous
//
#include <hip/hip_runtime.h>
#include <math.h>

#define NRES 512
#define HH 12
#define PQn 4
#define PVn 8
#define En 16
#define Cn 128
#define Sn 384
#define ATT_COLS 2112   // 192 att_single | 1536 att_pair | 288 points | 96 norms

// workspace float offsets
#define OFF_Q    0
#define OFF_K    (OFF_Q   + HH*NRES*En)
#define OFF_V    (OFF_K   + HH*NRES*En)
#define OFF_LQP  (OFF_V   + HH*NRES*En)
#define OFF_LKP  (OFF_LQP + HH*NRES*12)
#define OFF_LVP  (OFF_LKP + HH*NRES*12)
#define OFF_CS   (OFF_LVP + HH*NRES*24)     // colsum [H][N]
#define OFF_ATT  (OFF_CS  + NRES*HH)        // att [NRES][ATT_COLS]
#define OFF_LG   (OFF_ATT + NRES*ATT_COLS)  // logits/weights [H][N][N] (12.6 MB)
// out-GEMM partial buffer aliases LG (lg dead by then; both 3,145,728 floats)
#define OFF_PART OFF_LG
#define KSPLIT 16
#define KCHUNK (ATT_COLS/KSPLIT)   // 132
#define OROWS 8                    // rows per out-GEMM block (was 32: latency-bound)

// ---------------------------------------------------------------------------
// Kernel A: projections q/k/v and point projections with frame application.
// ---------------------------------------------------------------------------
__global__ __launch_bounds__(256) void ipa_proj(
    const float* __restrict__ single, const float* __restrict__ Rm,
    const float* __restrict__ tr,
    const float* __restrict__ Wq, const float* __restrict__ Wk,
    const float* __restrict__ Wv, const float* __restrict__ Wqp,
    const float* __restrict__ Wkp, const float* __restrict__ Wvp,
    float* __restrict__ ws)
{
  float* q   = ws + OFF_Q;  float* k   = ws + OFF_K;  float* v   = ws + OFF_V;
  float* lqp = ws + OFF_LQP; float* lkp = ws + OFF_LKP; float* lvp = ws + OFF_LVP;
  const int n0 = blockIdx.x * 8;
  const int g  = blockIdx.y;
  const int tid = threadIdx.x;
  __shared__ float sS[8][388];
  __shared__ float sR[8][9];
  __shared__ float sT[8][3];
  #pragma unroll
  for (int i = 0; i < 3; ++i) {
    int idx = i*256 + tid;
    int r = idx / 96, c4 = idx % 96;
    float4 val = *reinterpret_cast<const float4*>(single + (size_t)(n0 + r)*Sn + c4*4);
    *reinterpret_cast<float4*>(&sS[r][c4*4]) = val;
  }
  if (tid < 72)      sR[tid/9][tid%9] = Rm[(size_t)(n0 + tid/9)*9 + tid%9];
  else if (tid < 96) { int r = (tid-72)/3; sT[r][(tid-72)%3] = tr[(size_t)(n0+r)*3 + (tid-72)%3]; }
  __syncthreads();
  #pragma unroll
  for (int i = 0; i < 3; ++i) {
    int item = i*256 + tid;
    int nl = item & 7;
    int ul = item >> 3;
    int u  = g*96 + ul;
    const float* srow = sS[nl];
    if (u < 576) {
      int which = u/192, r = u%192, h = r>>4, e = r&15;
      const float* W = (which==0 ? Wq : which==1 ? Wk : Wv) + (size_t)h*Sn*En + e;
      float acc = 0.f;
      #pragma unroll 8
      for (int d = 0; d < Sn; ++d) acc = fmaf(srow[d], W[(size_t)d*En], acc);
      float* dst = (which==0 ? q : which==1 ? k : v);
      dst[((size_t)h*NRES + (n0+nl))*En + e] = acc;
    } else {
      int u2 = u - 576;
      const float* W; float* dst;
      if (u2 < 48)      { int h=u2>>2,     p=u2&3;      W = Wqp + (size_t)(h*PQn+p)*Sn*3; dst = lqp + ((size_t)h*NRES + (n0+nl))*12 + p*3; }
      else if (u2 < 96) { int h=(u2-48)>>2,p=(u2-48)&3; W = Wkp + (size_t)(h*PQn+p)*Sn*3; dst = lkp + ((size_t)h*NRES + (n0+nl))*12 + p*3; }
      else              { int h=(u2-96)>>3,p=(u2-96)&7; W = Wvp + (size_t)(h*PVn+p)*Sn*3; dst = lvp + ((size_t)h*NRES + (n0+nl))*24 + p*3; }
      float x0=0.f,x1=0.f,x2=0.f;
      #pragma unroll 4
      for (int d = 0; d < Sn; ++d) {
        float sv = srow[d];
        x0 = fmaf(sv, W[d*3+0], x0);
        x1 = fmaf(sv, W[d*3+1], x1);
        x2 = fmaf(sv, W[d*3+2], x2);
      }
      const float* R8 = sR[nl]; const float* T8 = sT[nl];
      dst[0] = R8[0]*x0 + R8[1]*x1 + R8[2]*x2 + T8[0];
      dst[1] = R8[3]*x0 + R8[4]*x1 + R8[5]*x2 + T8[1];
      dst[2] = R8[6]*x0 + R8[7]*x1 + R8[8]*x2 + T8[2];
    }
  }
}

// ---------------------------------------------------------------------------
// Kernel B: logits[h][n][m] = pair-bias + qk + frame. grid (512 n, 8 m-tiles).
// ---------------------------------------------------------------------------
__global__ __launch_bounds__(256) void ipa_logits(
    const float* __restrict__ pair, const float* __restrict__ Wb,
    const float* __restrict__ scale_head, float* __restrict__ ws)
{
  const float* q   = ws + OFF_Q;  const float* k   = ws + OFF_K;
  const float* lqp = ws + OFF_LQP; const float* lkp = ws + OFF_LKP;
  float* lg = ws + OFF_LG;
  const int n  = blockIdx.x;
  const int mt = blockIdx.y;
  const int tid = threadIdx.x;
  const int lane = tid & 63;
  const int wave = tid >> 6;
  const int h0 = wave*3;
  const int m0 = mt*64;

  __shared__ float tile[64*128];
  const float* src = pair + ((size_t)n*NRES + m0)*Cn;
  #pragma unroll
  for (int i = 0; i < 8; ++i) {
    int idx = i*256 + tid;
    int r = idx >> 5, cf = idx & 31;
    float4 val = *reinterpret_cast<const float4*>(src + (size_t)r*Cn + cf*4);
    *reinterpret_cast<float4*>(&tile[r*128 + ((cf ^ (r & 31)) << 2)]) = val;
  }
  __syncthreads();

  float p[3] = {0.f, 0.f, 0.f};
  #pragma unroll 8
  for (int c4 = 0; c4 < 32; ++c4) {
    float4 pv = *reinterpret_cast<const float4*>(&tile[lane*128 + ((c4 ^ (lane & 31)) << 2)]);
    float4 w0 = *reinterpret_cast<const float4*>(Wb + (h0+0)*Cn + c4*4);
    float4 w1 = *reinterpret_cast<const float4*>(Wb + (h0+1)*Cn + c4*4);
    float4 w2 = *reinterpret_cast<const float4*>(Wb + (h0+2)*Cn + c4*4);
    p[0] += pv.x*w0.x + pv.y*w0.y + pv.z*w0.z + pv.w*w0.w;
    p[1] += pv.x*w1.x + pv.y*w1.y + pv.z*w1.z + pv.w*w1.w;
    p[2] += pv.x*w2.x + pv.y*w2.y + pv.z*w2.z + pv.w*w2.w;
  }

  const int m = m0 + lane;
  #pragma unroll
  for (int i = 0; i < 3; ++i) {
    const int h = h0 + i;
    const float* qh = q + ((size_t)h*NRES + n)*En;
    const float* kh = k + ((size_t)h*NRES + m)*En;
    float qk = 0.f;
    #pragma unroll
    for (int e = 0; e < En; ++e) qk = fmaf(qh[e], kh[e], qk);
    const float* lq = lqp + ((size_t)h*NRES + n)*12;
    const float* lk = lkp + ((size_t)h*NRES + m)*12;
    float cross=0.f, Bm=0.f, An=0.f;
    #pragma unroll
    for (int jj = 0; jj < 12; ++jj) {
      float a = lq[jj], b = lk[jj];
      cross = fmaf(a, b, cross); Bm = fmaf(b, b, Bm); An = fmaf(a, a, An);
    }
    float gamma = 0.11785113019775793f * log1pf(__expf(scale_head[h]));
    lg[((size_t)h*NRES + n)*NRES + m] = p[i] + 0.25f*qk - gamma*(An + Bm - 2.f*cross);
  }
}

// ---------------------------------------------------------------------------
// Kernel C: softmax in place over last axis of lg[H][N][N]. One wave per row.
// ---------------------------------------------------------------------------
__global__ __launch_bounds__(256) void ipa_softmax(float* __restrict__ ws)
{
  float* lg = ws + OFF_LG;
  const int row  = blockIdx.x*4 + (threadIdx.x >> 6);
  const int lane = threadIdx.x & 63;
  float4* p = reinterpret_cast<float4*>(lg + (size_t)row*NRES);
  float4 x0 = p[lane];
  float4 x1 = p[64 + lane];
  float mx = fmaxf(fmaxf(fmaxf(x0.x,x0.y),fmaxf(x0.z,x0.w)),
                   fmaxf(fmaxf(x1.x,x1.y),fmaxf(x1.z,x1.w)));
  #pragma unroll
  for (int off = 32; off >= 1; off >>= 1) mx = fmaxf(mx, __shfl_xor(mx, off));
  x0.x = __expf(x0.x-mx); x0.y = __expf(x0.y-mx); x0.z = __expf(x0.z-mx); x0.w = __expf(x0.w-mx);
  x1.x = __expf(x1.x-mx); x1.y = __expf(x1.y-mx); x1.z = __expf(x1.z-mx); x1.w = __expf(x1.w-mx);
  float sum = x0.x+x0.y+x0.z+x0.w + x1.x+x1.y+x1.z+x1.w;
  #pragma unroll
  for (int off = 32; off >= 1; off >>= 1) sum += __shfl_xor(sum, off);
  const float inv = 1.f/sum;
  x0.x*=inv; x0.y*=inv; x0.z*=inv; x0.w*=inv;
  x1.x*=inv; x1.y*=inv; x1.z*=inv; x1.w*=inv;
  p[lane] = x0;
  p[64 + lane] = x1;
}

// ---------------------------------------------------------------------------
// Kernel D: colsum[h][b] = sum_a w[h][a][b]. grid (12, 8 a-chunks).
// ---------------------------------------------------------------------------
__global__ __launch_bounds__(256) void ipa_colsum(float* __restrict__ ws)
{
  const float* lg = ws + OFF_LG;
  float* cs = ws + OFF_CS;
  const int h = blockIdx.x, ac = blockIdx.y, tid = threadIdx.x;
  const float* base = lg + (size_t)h*NRES*NRES + (size_t)ac*64*NRES;
  float acc0 = 0.f, acc1 = 0.f;
  #pragma unroll 4
  for (int a = 0; a < 64; ++a) {
    acc0 += base[(size_t)a*NRES + tid];
    acc1 += base[(size_t)a*NRES + tid + 256];
  }
  atomicAdd(&cs[h*NRES + tid],       acc0);
  atomicAdd(&cs[h*NRES + tid + 256], acc1);
}

// ---------------------------------------------------------------------------
// Kernel E: att_single = w.v, local_out = w.lvp, inverse frame + norms.
// ---------------------------------------------------------------------------
__global__ __launch_bounds__(256) void ipa_agg(
    const float* __restrict__ Rm, const float* __restrict__ tr,
    float* __restrict__ ws)
{
  const float* v   = ws + OFF_V;
  const float* lvp = ws + OFF_LVP;
  const float* lg  = ws + OFF_LG;
  float* att = ws + OFF_ATT;
  const int row  = blockIdx.x*4 + (threadIdx.x >> 6);
  const int lane = threadIdx.x & 63;
  const int h = row >> 9, n = row & 511;

  float acc[40];
  #pragma unroll
  for (int i = 0; i < 40; ++i) acc[i] = 0.f;

  const float* wrow = lg + (size_t)row*NRES;
  #pragma unroll 2
  for (int j = 0; j < 8; ++j) {
    const int m = j*64 + lane;
    const float wv = wrow[m];
    const float4* v4 = reinterpret_cast<const float4*>(v + ((size_t)h*NRES + m)*En);
    float4 a0=v4[0], a1=v4[1], a2=v4[2], a3=v4[3];
    acc[0]+=wv*a0.x; acc[1]+=wv*a0.y; acc[2]+=wv*a0.z; acc[3]+=wv*a0.w;
    acc[4]+=wv*a1.x; acc[5]+=wv*a1.y; acc[6]+=wv*a1.z; acc[7]+=wv*a1.w;
    acc[8]+=wv*a2.x; acc[9]+=wv*a2.y; acc[10]+=wv*a2.z; acc[11]+=wv*a2.w;
    acc[12]+=wv*a3.x; acc[13]+=wv*a3.y; acc[14]+=wv*a3.z; acc[15]+=wv*a3.w;
    const float4* l4 = reinterpret_cast<const float4*>(lvp + ((size_t)h*NRES + m)*24);
    #pragma unroll
    for (int t = 0; t < 6; ++t) {
      float4 b = l4[t];
      acc[16+4*t+0]+=wv*b.x; acc[16+4*t+1]+=wv*b.y;
      acc[16+4*t+2]+=wv*b.z; acc[16+4*t+3]+=wv*b.w;
    }
  }
  #pragma unroll
  for (int off = 32; off >= 1; off >>= 1) {
    #pragma unroll
    for (int i = 0; i < 40; ++i) acc[i] += __shfl_xor(acc[i], off);
  }
  if (lane == 0) {
    size_t ab = (size_t)n*ATT_COLS;
    float4* as = reinterpret_cast<float4*>(att + ab + h*En);
    as[0] = make_float4(acc[0],acc[1],acc[2],acc[3]);
    as[1] = make_float4(acc[4],acc[5],acc[6],acc[7]);
    as[2] = make_float4(acc[8],acc[9],acc[10],acc[11]);
    as[3] = make_float4(acc[12],acc[13],acc[14],acc[15]);
    const float R0=Rm[n*9+0],R1=Rm[n*9+1],R2=Rm[n*9+2],
                R3=Rm[n*9+3],R4=Rm[n*9+4],R5=Rm[n*9+5],
                R6=Rm[n*9+6],R7=Rm[n*9+7],R8=Rm[n*9+8];
    const float t0=tr[n*3+0], t1=tr[n*3+1], t2=tr[n*3+2];
    #pragma unroll
    for (int pp = 0; pp < 8; ++pp) {
      float d0 = acc[16+3*pp+0]-t0, d1 = acc[16+3*pp+1]-t1, d2 = acc[16+3*pp+2]-t2;
      float g0 = R0*d0 + R3*d1 + R6*d2;
      float g1 = R1*d0 + R4*d1 + R7*d2;
      float g2 = R2*d0 + R5*d1 + R8*d2;
      att[ab + 1728 + (pp*HH + h)*3 + 0] = g0;
      att[ab + 1728 + (pp*HH + h)*3 + 1] = g1;
      att[ab + 1728 + (pp*HH + h)*3 + 2] = g2;
      att[ab + 2016 + pp*HH + h] = sqrtf(g0*g0 + g1*g1 + g2*g2);
    }
  }
}

// ---------------------------------------------------------------------------
// Kernel F: att_pair[h,i,c] = sum_b colsum[h,b]*pair[i,b,c]. One block per i.
// ---------------------------------------------------------------------------
__global__ __launch_bounds__(256) void ipa_pairagg(
    const float* __restrict__ pair, float* __restrict__ ws)
{
  const float* cs = ws + OFF_CS;
  float* att = ws + OFF_ATT;
  const int i = blockIdx.x, tid = threadIdx.x;
  __shared__ float sCS[HH*NRES];
  __shared__ float4 sRed[8][HH][32];
  #pragma unroll
  for (int it = 0; it < 6; ++it) {
    int idx = it*256 + tid;
    reinterpret_cast<float4*>(sCS)[idx] = reinterpret_cast<const float4*>(cs)[idx];
  }
  __syncthreads();
  const int c4 = tid & 31, bg = tid >> 5;
  float4 acc[HH];
  #pragma unroll
  for (int h = 0; h < HH; ++h) acc[h] = make_float4(0.f,0.f,0.f,0.f);
  const float* prow = pair + (size_t)i*NRES*Cn;
  for (int b = bg; b < NRES; b += 8) {
    float4 pv = *reinterpret_cast<const float4*>(prow + (size_t)b*Cn + c4*4);
    #pragma unroll
    for (int h = 0; h < HH; ++h) {
      float w = sCS[h*NRES + b];
      acc[h].x = fmaf(w, pv.x, acc[h].x);
      acc[h].y = fmaf(w, pv.y, acc[h].y);
      acc[h].z = fmaf(w, pv.z, acc[h].z);
      acc[h].w = fmaf(w, pv.w, acc[h].w);
    }
  }
  #pragma unroll
  for (int h = 0; h < HH; ++h) sRed[bg][h][c4] = acc[h];
  __syncthreads();
  for (int s = 4; s >= 1; s >>= 1) {
    if (bg < s) {
      #pragma unroll
      for (int h = 0; h < HH; ++h) {
        float4 a = sRed[bg][h][c4], b2 = sRed[bg+s][h][c4];
        a.x+=b2.x; a.y+=b2.y; a.z+=b2.z; a.w+=b2.w;
        sRed[bg][h][c4] = a;
      }
    }
    __syncthreads();
  }
  if (bg == 0) {
    size_t base = (size_t)i*ATT_COLS + 192;
    #pragma unroll
    for (int h = 0; h < HH; ++h)
      *reinterpret_cast<float4*>(att + base + h*Cn + c4*4) = sRed[0][h][c4];
  }
}

// ---------------------------------------------------------------------------
// Kernel G1: split-k partial GEMM. grid (64 rowblocks, 16 ksplits), 384 thr.
// OROWS=8 rows/block -> 1024 blocks, 4 blocks/CU, 24 waves/CU: latency hidden
// by TLP. att loads thread-uniform (scalarized); Wout coalesced over s.
// ---------------------------------------------------------------------------
__global__ __launch_bounds__(384) void ipa_outp(
    const float* __restrict__ att, const float* __restrict__ Wout,
    float* __restrict__ ws)
{
  float* partial = ws + OFF_PART;       // [KSPLIT][NRES][Sn]
  const int rb = blockIdx.x;            // OROWS rows each
  const int ks = blockIdx.y;            // 132 k each
  const int s  = threadIdx.x;
  const int n0 = rb*OROWS;
  const int j0 = ks*KCHUNK;

  float acc[OROWS];
  #pragma unroll
  for (int r = 0; r < OROWS; ++r) acc[r] = 0.f;

  for (int jg = 0; jg < KCHUNK/4; ++jg) {
    const int j = j0 + jg*4;
    float w0 = Wout[(size_t)(j+0)*Sn + s];
    float w1 = Wout[(size_t)(j+1)*Sn + s];
    float w2 = Wout[(size_t)(j+2)*Sn + s];
    float w3 = Wout[(size_t)(j+3)*Sn + s];
    #pragma unroll
    for (int r = 0; r < OROWS; ++r) {
      float4 av = *reinterpret_cast<const float4*>(att + (size_t)(n0+r)*ATT_COLS + j);
      acc[r] = fmaf(av.x, w0, acc[r]);
      acc[r] = fmaf(av.y, w1, acc[r]);
      acc[r] = fmaf(av.z, w2, acc[r]);
      acc[r] = fmaf(av.w, w3, acc[r]);
    }
  }
  #pragma unroll
  for (int r = 0; r < OROWS; ++r)
    partial[((size_t)ks*NRES + n0 + r)*Sn + s] = acc[r];
}

// ---------------------------------------------------------------------------
// Kernel G2: out[n][s] = b_out[s] + sum_ks partial[ks][n][s].
// ---------------------------------------------------------------------------
__global__ __launch_bounds__(384) void ipa_outred(
    const float* __restrict__ b_out, float* __restrict__ ws,
    float* __restrict__ out)
{
  const float* partial = ws + OFF_PART;
  const int n = blockIdx.x, s = threadIdx.x;
  float a = b_out[s];
  #pragma unroll
  for (int ks = 0; ks < KSPLIT; ++ks)
    a += partial[((size_t)ks*NRES + n)*Sn + s];
  out[(size_t)n*Sn + s] = a;
}

// ---------------------------------------------------------------------------
extern "C" void kernel_launch(void* const* d_in, const int* in_sizes, int n_in,
                              void* d_out, int out_size, void* d_ws, size_t ws_size,
                              hipStream_t stream) {
  const float* single = (const float*)d_in[0];
  const float* pair   = (const float*)d_in[1];
  const float* Rm     = (const float*)d_in[2];
  const float* tr     = (const float*)d_in[3];
  const float* Wq     = (const float*)d_in[4];
  const float* Wk     = (const float*)d_in[5];
  const float* Wv     = (const float*)d_in[6];
  const float* Wqp    = (const float*)d_in[7];
  const float* Wkp    = (const float*)d_in[8];
  const float* Wvp    = (const float*)d_in[9];
  const float* Wb     = (const float*)d_in[10];
  const float* Wout   = (const float*)d_in[11];
  const float* b_out  = (const float*)d_in[12];
  const float* scale_head = (const float*)d_in[13];
  float* ws  = (float*)d_ws;
  float* out = (float*)d_out;

  hipMemsetAsync(ws + OFF_CS, 0, NRES*HH*sizeof(float), stream);
  ipa_proj   <<<dim3(64, 8),  256, 0, stream>>>(single, Rm, tr, Wq, Wk, Wv, Wqp, Wkp, Wvp, ws);
  ipa_logits <<<dim3(NRES, 8),256, 0, stream>>>(pair, Wb, scale_head, ws);
  ipa_softmax<<<dim3(HH*NRES/4), 256, 0, stream>>>(ws);
  ipa_colsum <<<dim3(HH, 8),  256, 0, stream>>>(ws);
  ipa_agg    <<<dim3(HH*NRES/4), 256, 0, stream>>>(Rm, tr, ws);
  ipa_pairagg<<<dim3(NRES),   256, 0, stream>>>(pair, ws);
  ipa_outp   <<<dim3(NRES/OROWS, KSPLIT), 384, 0, stream>>>(ws + OFF_ATT, Wout, ws);
  ipa_outred <<<dim3(NRES),   384, 0, stream>>>(b_out, ws, out);
}